// Round 18
// baseline (128.253 us; speedup 1.0000x reference)
//
#include <hip/hip_runtime.h>
#include <hip/hip_bf16.h>

#define B_ 2
#define T_ 2048
#define C_ 1024
#define NH_ 16
#define HD_ 64

using bf16 = __hip_bfloat16;
typedef __attribute__((ext_vector_type(8))) short bf16x8;
typedef __attribute__((ext_vector_type(4))) float f32x4;
typedef __attribute__((ext_vector_type(16))) float f32x16;

__device__ __forceinline__ float bf2f(unsigned short u) {
    union { unsigned int i; float f; } v;
    v.i = ((unsigned int)u) << 16;
    return v.f;
}
__device__ __forceinline__ unsigned short f2bf(float f) {
    union { float f; unsigned int u; } v;
    v.f = f;
    unsigned int r = v.u + 0x7fffu + ((v.u >> 16) & 1u);  // RNE
    return (unsigned short)(r >> 16);
}
// pack 2 fp32 -> 2 bf16 (RNE) in one instruction; lo in bits 0-15
__device__ __forceinline__ unsigned int cvt_pk_bf16(float lo, float hi) {
    unsigned int r;
    asm("v_cvt_pk_bf16_f32 %0, %1, %2" : "=v"(r) : "v"(lo), "v"(hi));
    return r;
}
__device__ __forceinline__ void gld_lds16(const void* g, void* l) {
    __builtin_amdgcn_global_load_lds(
        (__attribute__((address_space(1))) void*)g,
        (__attribute__((address_space(3))) void*)l, 16, 0, 0);
}

// ---------------------------------------------------------------------------
// prep: fused cast_bf16(x) [blocks 0..2047] + transpose_cast(w_qkv)
// [blocks 2048..2815].
// ---------------------------------------------------------------------------
__global__ __launch_bounds__(256) void prep(
    const float* __restrict__ X, const float* __restrict__ Wq,
    unsigned short* __restrict__ Xb, unsigned short* __restrict__ Wqt) {
    __shared__ short S[64][72];
    const int b = blockIdx.x;
    const int t = threadIdx.x;
    if (b < 2048) {
        int i = (b * 256 + t) * 8;
        float4 f0 = *reinterpret_cast<const float4*>(&X[i]);
        float4 f1 = *reinterpret_cast<const float4*>(&X[i + 4]);
        union { unsigned short s[8]; uint4 v; } o;
        o.s[0] = f2bf(f0.x); o.s[1] = f2bf(f0.y); o.s[2] = f2bf(f0.z); o.s[3] = f2bf(f0.w);
        o.s[4] = f2bf(f1.x); o.s[5] = f2bf(f1.y); o.s[6] = f2bf(f1.z); o.s[7] = f2bf(f1.w);
        *reinterpret_cast<uint4*>(&Xb[i]) = o.v;
        return;
    }
    const int idx = b - 2048;                // 0..767 = 48 x-tiles * 16 y-tiles
    const int n0 = (idx % 48) * 64, k0 = (idx / 48) * 64;
    const int NN = 3 * C_, KK = C_;
    const int lr = t >> 2, lc = (t & 3) * 16;
    const float* src = &Wq[(size_t)(k0 + lr) * NN + n0 + lc];
    #pragma unroll
    for (int j4 = 0; j4 < 4; ++j4) {
        float4 f = *reinterpret_cast<const float4*>(src + j4 * 4);
        S[lc + j4 * 4 + 0][lr] = (short)f2bf(f.x);
        S[lc + j4 * 4 + 1][lr] = (short)f2bf(f.y);
        S[lc + j4 * 4 + 2][lr] = (short)f2bf(f.z);
        S[lc + j4 * 4 + 3][lr] = (short)f2bf(f.w);
    }
    __syncthreads();
    union { unsigned short s[16]; uint4 v[2]; } o;
    #pragma unroll
    for (int j = 0; j < 16; ++j) o.s[j] = (unsigned short)S[lr][lc + j];
    unsigned short* dst = &Wqt[(size_t)(n0 + lr) * KK + k0 + lc];
    *reinterpret_cast<uint4*>(dst)     = o.v[0];
    *reinterpret_cast<uint4*>(dst + 8) = o.v[1];
}

// ---------------------------------------------------------------------------
// post: fused transpose_v [blocks 0..1023] + transpose_cast(w_proj)
// [blocks 1024..1279].
// ---------------------------------------------------------------------------
__global__ __launch_bounds__(256) void post(
    const unsigned short* __restrict__ V, unsigned short* __restrict__ Vt,
    const float* __restrict__ Wp, unsigned short* __restrict__ Wpt) {
    __shared__ short S[64][72];
    const int b = blockIdx.x;
    const int t = threadIdx.x;
    const int lr = t >> 2, lc = (t & 3) * 16;
    if (b < 1024) {
        const int bh = b >> 5, t0 = (b & 31) * 64;
        const unsigned short* src = V + ((size_t)bh * T_ + t0 + lr) * HD_ + lc;
        union { uint4 v[2]; unsigned short s[16]; } u;
        u.v[0] = *reinterpret_cast<const uint4*>(src);
        u.v[1] = *reinterpret_cast<const uint4*>(src + 8);
        #pragma unroll
        for (int j = 0; j < 16; ++j) S[lc + j][lr] = (short)u.s[j];
        __syncthreads();
        union { unsigned short s[16]; uint4 v[2]; } o;
        #pragma unroll
        for (int j = 0; j < 16; ++j) o.s[j] = (unsigned short)S[lr][lc + j];
        unsigned short* dst = Vt + ((size_t)bh * HD_ + lr) * T_ + t0 + lc;
        *reinterpret_cast<uint4*>(dst)     = o.v[0];
        *reinterpret_cast<uint4*>(dst + 8) = o.v[1];
        return;
    }
    const int idx = b - 1024;                // 0..255 = 16x16
    const int n0 = (idx & 15) * 64, k0 = (idx >> 4) * 64;
    const float* src = &Wp[(size_t)(k0 + lr) * C_ + n0 + lc];
    #pragma unroll
    for (int j4 = 0; j4 < 4; ++j4) {
        float4 f = *reinterpret_cast<const float4*>(src + j4 * 4);
        S[lc + j4 * 4 + 0][lr] = (short)f2bf(f.x);
        S[lc + j4 * 4 + 1][lr] = (short)f2bf(f.y);
        S[lc + j4 * 4 + 2][lr] = (short)f2bf(f.z);
        S[lc + j4 * 4 + 3][lr] = (short)f2bf(f.w);
    }
    __syncthreads();
    union { unsigned short s[16]; uint4 v[2]; } o;
    #pragma unroll
    for (int j = 0; j < 16; ++j) o.s[j] = (unsigned short)S[lr][lc + j];
    unsigned short* dst = &Wpt[(size_t)(n0 + lr) * C_ + k0 + lc];
    *reinterpret_cast<uint4*>(dst)     = o.v[0];
    *reinterpret_cast<uint4*>(dst + 8) = o.v[1];
}

// ---------------------------------------------------------------------------
// QKV GEMM, bf16 MFMA, dbuf single-barrier (r17). Q pre-scaled by log2e/8;
// XCD swizzle (768 = 8x96).
// ---------------------------------------------------------------------------
__global__ __launch_bounds__(256) void qkv_gemm_mfma(
    const unsigned short* __restrict__ A, const unsigned short* __restrict__ Bt,
    unsigned short* __restrict__ Qb, unsigned short* __restrict__ Kb,
    unsigned short* __restrict__ Vb) {
    __shared__ short As[2][128 * 32];
    __shared__ short Bs[2][128 * 32];
    const int t = threadIdx.x;
    const int wid = t >> 6, lane = t & 63;
    const int wm = wid >> 1, wn = wid & 1;
    const int c = lane & 15, g = lane >> 4;
    const int dd = blockIdx.x;
    const int w  = (dd & 7) * 96 + (dd >> 3);
    const int m0 = (w / 24) * 128, n0 = (w % 24) * 128;
    const int K = C_;
    const int srow = t >> 2, skk = (t & 3) * 8;

    f32x4 acc[4][4];
    #pragma unroll
    for (int i = 0; i < 4; ++i)
        #pragma unroll
        for (int j = 0; j < 4; ++j) acc[i][j] = (f32x4){0.f, 0.f, 0.f, 0.f};

    gld_lds16(&A[(size_t)(m0 + srow) * K + skk],       As[0] + t * 8);
    gld_lds16(&A[(size_t)(m0 + 64 + srow) * K + skk],  As[0] + 2048 + t * 8);
    gld_lds16(&Bt[(size_t)(n0 + srow) * K + skk],      Bs[0] + t * 8);
    gld_lds16(&Bt[(size_t)(n0 + 64 + srow) * K + skk], Bs[0] + 2048 + t * 8);

    #pragma unroll 1
    for (int kt = 0; kt < 32; ++kt) {
        const int cur = kt & 1;
        __syncthreads();
        if (kt < 31) {
            const int k0 = (kt + 1) * 32;
            gld_lds16(&A[(size_t)(m0 + srow) * K + k0 + skk],       As[cur ^ 1] + t * 8);
            gld_lds16(&A[(size_t)(m0 + 64 + srow) * K + k0 + skk],  As[cur ^ 1] + 2048 + t * 8);
            gld_lds16(&Bt[(size_t)(n0 + srow) * K + k0 + skk],      Bs[cur ^ 1] + t * 8);
            gld_lds16(&Bt[(size_t)(n0 + 64 + srow) * K + k0 + skk], Bs[cur ^ 1] + 2048 + t * 8);
        }
        bf16x8 af[4], bfv[4];
        #pragma unroll
        for (int mi = 0; mi < 4; ++mi)
            af[mi] = *reinterpret_cast<const bf16x8*>(&As[cur][(wm * 64 + mi * 16 + c) * 32 + g * 8]);
        #pragma unroll
        for (int ni = 0; ni < 4; ++ni)
            bfv[ni] = *reinterpret_cast<const bf16x8*>(&Bs[cur][(wn * 64 + ni * 16 + c) * 32 + g * 8]);
        #pragma unroll
        for (int mi = 0; mi < 4; ++mi)
            #pragma unroll
            for (int ni = 0; ni < 4; ++ni)
                acc[mi][ni] = __builtin_amdgcn_mfma_f32_16x16x32_bf16(af[mi], bfv[ni], acc[mi][ni], 0, 0, 0);
    }

    const int nbase = n0 + wn * 64;
    const int which = nbase >> 10;
    const int h     = (nbase >> 6) & (NH_ - 1);
    // Q scale: 1/sqrt(HD) * log2(e)  (attn softmax runs in exp2 domain)
    const float scale = (which == 0) ? 0.125f * 1.44269504f : 1.0f;
    unsigned short* dst = (which == 0) ? Qb : ((which == 1) ? Kb : Vb);
    #pragma unroll
    for (int mi = 0; mi < 4; ++mi)
        #pragma unroll
        for (int r = 0; r < 4; ++r) {
            const int m = m0 + wm * 64 + mi * 16 + 4 * g + r;
            const int bb = m >> 11, tq = m & (T_ - 1);
            unsigned short* p = dst + ((size_t)((bb << 4) | h) * T_ + tq) * HD_;
            #pragma unroll
            for (int ni = 0; ni < 4; ++ni)
                p[ni * 16 + c] = f2bf(acc[mi][ni][r] * scale);
        }
}

// ---------------------------------------------------------------------------
// Projection GEMM, bf16 MFMA, 64x128 tile, dbuf single-barrier loop.
// ---------------------------------------------------------------------------
__global__ __launch_bounds__(256) void proj_gemm_mfma(
    const unsigned short* __restrict__ A, const unsigned short* __restrict__ Bt,
    float* __restrict__ Out) {
    __shared__ short As[2][64 * 32];
    __shared__ short Bs[2][128 * 32];
    const int t = threadIdx.x;
    const int wid = t >> 6, lane = t & 63;
    const int wm = wid >> 1, wn = wid & 1;
    const int c = lane & 15, g = lane >> 4;
    const int m0 = blockIdx.y * 64, n0 = blockIdx.x * 128;
    const int K = C_;
    const int srow = t >> 2, skk = (t & 3) * 8;

    f32x4 acc[2][4];
    #pragma unroll
    for (int i = 0; i < 2; ++i)
        #pragma unroll
        for (int j = 0; j < 4; ++j) acc[i][j] = (f32x4){0.f, 0.f, 0.f, 0.f};

    gld_lds16(&A[(size_t)(m0 + srow) * K + skk],       As[0] + t * 8);
    gld_lds16(&Bt[(size_t)(n0 + srow) * K + skk],      Bs[0] + t * 8);
    gld_lds16(&Bt[(size_t)(n0 + 64 + srow) * K + skk], Bs[0] + 2048 + t * 8);

    #pragma unroll 1
    for (int kt = 0; kt < 32; ++kt) {
        const int cur = kt & 1;
        __syncthreads();
        if (kt < 31) {
            const int k0 = (kt + 1) * 32;
            gld_lds16(&A[(size_t)(m0 + srow) * K + k0 + skk],       As[cur ^ 1] + t * 8);
            gld_lds16(&Bt[(size_t)(n0 + srow) * K + k0 + skk],      Bs[cur ^ 1] + t * 8);
            gld_lds16(&Bt[(size_t)(n0 + 64 + srow) * K + k0 + skk], Bs[cur ^ 1] + 2048 + t * 8);
        }
        bf16x8 af[2], bfv[4];
        #pragma unroll
        for (int mi = 0; mi < 2; ++mi)
            af[mi] = *reinterpret_cast<const bf16x8*>(&As[cur][(wm * 32 + mi * 16 + c) * 32 + g * 8]);
        #pragma unroll
        for (int ni = 0; ni < 4; ++ni)
            bfv[ni] = *reinterpret_cast<const bf16x8*>(&Bs[cur][(wn * 64 + ni * 16 + c) * 32 + g * 8]);
        #pragma unroll
        for (int mi = 0; mi < 2; ++mi)
            #pragma unroll
            for (int ni = 0; ni < 4; ++ni)
                acc[mi][ni] = __builtin_amdgcn_mfma_f32_16x16x32_bf16(af[mi], bfv[ni], acc[mi][ni], 0, 0, 0);
    }

    #pragma unroll
    for (int mi = 0; mi < 2; ++mi)
        #pragma unroll
        for (int r = 0; r < 4; ++r) {
            const int m = m0 + wm * 32 + mi * 16 + 4 * g + r;
            float* p = Out + (size_t)m * C_ + n0 + wn * 64;
            #pragma unroll
            for (int ni = 0; ni < 4; ++ni)
                p[ni * 16 + c] = acc[mi][ni][r];
        }
}

// ---------------------------------------------------------------------------
// Flash attention, ROUND-18: mfma_f32_32x32x16_bf16.
// 256 threads / 4 waves; waves 0-1 own q-tile A (qtA=2u), waves 2-3 own
// q-tile B (qtB=2u+1); each wave covers 32 q-rows. Per q-row LDS fragment
// traffic HALVES vs the 16x16 shape (wave reads K/V once for 32 rows).
// Swapped QK^T: sacc = mfma(K_frag, Q_frag) -> lane holds S[q=lane&31][16 j]
// per j-subtile; softmax fully lane-local (no cross-lane ops in loop).
// PV: y^T = mfma(V^T_frag, P_frag): P is the lane's own cvt_pk words via
// j-permutation kappa(j) = ((j>>3)&3)*16 + ((j>>2)&1)*8 + (j>>5)*4 + (j&3);
// V staged at kappa slots (4x 8B per-thread-constant writes).
// Layouts (32x32x16): A row=l&31, k=(l>>5)*8+i; B col=l&31, same k;
// C/D col=l&31, row=(r&3)+8*(r>>2)+4*(l>>5)  [verified m74/m101].
// Dbuf K/V, one barrier/iter; 2 blocks/CU (36KB LDS, launch_bounds(256,2)).
// Decode: blocks (d, d+256) complementary u -> per-CU iter sum 34; bh%8=XCD.
// ---------------------------------------------------------------------------
__global__ __launch_bounds__(256, 2) void attn_mfma(
    const unsigned short* __restrict__ Qb, const unsigned short* __restrict__ Kb,
    const unsigned short* __restrict__ Vt_g, unsigned short* __restrict__ Yu) {
    __shared__ short Ks[2][64][72];     // [buf][j][d]
    __shared__ short Vt[2][64][72];     // [buf][d][kappa]

    const int t    = threadIdx.x;
    const int wid  = t >> 6;            // 0..3
    const int lane = t & 63;
    const int ql   = lane & 31;         // q within wave's 32 rows; also out col
    const int h    = lane >> 5;         // k-half selector

    // --- block decode ---
    const int d   = blockIdx.x;              // 0..511
    const int xcd = d & 7;
    const int tt  = d >> 3;                  // 0..63
    const int up  = tt & 15;
    const int k2  = tt >> 4;                 // 0..3
    const int bh  = (k2 << 3) | xcd;
    const int u   = (k2 & 2) ? (15 - up) : up;
    const int qtB = 2 * u + 1;
    const int myqt = (wid < 2) ? (2 * u) : qtB;

    const int bb = bh >> 4, hh = bh & (NH_ - 1);
    const int qglob = myqt * 64 + (wid & 1) * 32 + ql;   // this lane's q-row

    const unsigned short* Qh  = Qb   + (size_t)bh * T_ * HD_;
    const unsigned short* Kh  = Kb   + (size_t)bh * T_ * HD_;
    const unsigned short* VTh = Vt_g + (size_t)bh * HD_ * T_;

    // staging: 256 threads, 32B K + 32B V each
    const int srow = t >> 2, scol = (t & 3) * 16;
    int kap[4];
    #pragma unroll
    for (int m = 0; m < 4; ++m) {
        const int j = scol + 4 * m;
        kap[m] = ((j >> 3) & 3) * 16 + ((j >> 2) & 1) * 8 + (j >> 5) * 4;
    }

    // Q fragments in registers (pre-scaled by log2e/8): qf[s] covers
    // d = s*16 + 8h .. +8 for q-row qglob.
    bf16x8 qf[4];
    {
        const unsigned short* qs = Qh + (size_t)qglob * HD_ + 8 * h;
        #pragma unroll
        for (int s = 0; s < 4; ++s)
            qf[s] = *reinterpret_cast<const bf16x8*>(qs + s * 16);
    }

    float l_run = 0.f;
    f32x16 yacc[2];
    yacc[0] = (f32x16)(0.f);
    yacc[1] = (f32x16)(0.f);

    // prologue: load tile 0 into regs
    uint4 kv0, kv1, vv0, vv1;
    {
        const unsigned short* ks = &Kh[(size_t)srow * HD_ + scol];
        kv0 = *reinterpret_cast<const uint4*>(ks);
        kv1 = *reinterpret_cast<const uint4*>(ks + 8);
        const unsigned short* vs = &VTh[(size_t)srow * T_ + scol];
        vv0 = *reinterpret_cast<const uint4*>(vs);
        vv1 = *reinterpret_cast<const uint4*>(vs + 8);
    }

    #pragma unroll 1
    for (int kt = 0; kt <= qtB; ++kt) {
        const int cur = kt & 1;
        *reinterpret_cast<uint4*>(&Ks[cur][srow][scol])     = kv0;
        *reinterpret_cast<uint4*>(&Ks[cur][srow][scol + 8]) = kv1;
        *reinterpret_cast<uint2*>(&Vt[cur][srow][kap[0]]) = make_uint2(vv0.x, vv0.y);
        *reinterpret_cast<uint2*>(&Vt[cur][srow][kap[1]]) = make_uint2(vv0.z, vv0.w);
        *reinterpret_cast<uint2*>(&Vt[cur][srow][kap[2]]) = make_uint2(vv1.x, vv1.y);
        *reinterpret_cast<uint2*>(&Vt[cur][srow][kap[3]]) = make_uint2(vv1.z, vv1.w);
        __syncthreads();            // staging visible; gates next write of buf^1

        if (kt < qtB) {             // issue next tile's loads; land during compute
            const int j1 = (kt + 1) * 64;
            const unsigned short* ks = &Kh[(size_t)(j1 + srow) * HD_ + scol];
            kv0 = *reinterpret_cast<const uint4*>(ks);
            kv1 = *reinterpret_cast<const uint4*>(ks + 8);
            const unsigned short* vs = &VTh[(size_t)srow * T_ + j1 + scol];
            vv0 = *reinterpret_cast<const uint4*>(vs);
            vv1 = *reinterpret_cast<const uint4*>(vs + 8);
        }

        if (kt <= myqt) {
            // ---- S^T = K Q^T : 8 MFMA (2 j-subtiles x 4 d-slices) ----
            f32x16 sacc[2];
            sacc[0] = (f32x16)(0.f);
            sacc[1] = (f32x16)(0.f);
            __builtin_amdgcn_s_setprio(1);
            #pragma unroll
            for (int s = 0; s < 4; ++s) {
                #pragma unroll
                for (int nt = 0; nt < 2; ++nt) {
                    bf16x8 kf = *reinterpret_cast<const bf16x8*>(
                        &Ks[cur][nt * 32 + ql][s * 16 + 8 * h]);
                    sacc[nt] = __builtin_amdgcn_mfma_f32_32x32x16_bf16(kf, qf[s], sacc[nt], 0, 0, 0);
                }
            }
            __builtin_amdgcn_s_setprio(0);

            // ---- static-max softmax (exp2 domain, fully lane-local) ----
            const bool diag = (kt == myqt);
            float p[2][16];
            float lsum = 0.f;
            #pragma unroll
            for (int nt = 0; nt < 2; ++nt)
                #pragma unroll
                for (int r = 0; r < 16; ++r) {
                    float s = sacc[nt][r];
                    if (diag) {
                        const int jg = kt * 64 + nt * 32 + (r & 3) + 8 * (r >> 2) + 4 * h;
                        if (jg > qglob) s = -1e30f;
                    }
                    float pv = exp2f(s);
                    p[nt][r] = pv;
                    lsum += pv;
                }
            l_run += lsum;          // lane partial (pair lane^32 holds rest)

            // ---- y^T += V^T P : 8 MFMA. B = lane's own packed P words ----
            __builtin_amdgcn_s_setprio(1);
            #pragma unroll
            for (int s = 0; s < 4; ++s) {
                union { unsigned int w[4]; bf16x8 v; } pb;
                pb.w[0] = cvt_pk_bf16(p[0][4 * s + 0], p[0][4 * s + 1]);
                pb.w[1] = cvt_pk_bf16(p[0][4 * s + 2], p[0][4 * s + 3]);
                pb.w[2] = cvt_pk_bf16(p[1][4 * s + 0], p[1][4 * s + 1]);
                pb.w[3] = cvt_pk_bf16(p[1][4 * s + 2], p[1][4 * s + 3]);
                #pragma unroll
                for (int dt = 0; dt < 2; ++dt) {
                    bf16x8 vf = *reinterpret_cast<const bf16x8*>(
                        &Vt[cur][dt * 32 + ql][s * 16 + 8 * h]);
                    yacc[dt] = __builtin_amdgcn_mfma_f32_32x32x16_bf16(vf, pb.v, yacc[dt], 0, 0, 0);
                }
            }
            __builtin_amdgcn_s_setprio(0);
        }
    }

    // ---- epilogue: one shfl for l; lane-local normalize; 8B stores ----
    float lf = l_run;
    lf += __shfl_xor(lf, 32, 64);
    const float inv = 1.0f / lf;              // for q-row qglob
    unsigned short* base = &Yu[(size_t)(bb * T_ + qglob) * C_ + hh * HD_];
    #pragma unroll
    for (int dt = 0; dt < 2; ++dt)
        #pragma unroll
        for (int b4 = 0; b4 < 4; ++b4) {
            uint2 ow;
            ow.x = cvt_pk_bf16(yacc[dt][4 * b4 + 0] * inv, yacc[dt][4 * b4 + 1] * inv);
            ow.y = cvt_pk_bf16(yacc[dt][4 * b4 + 2] * inv, yacc[dt][4 * b4 + 3] * inv);
            *reinterpret_cast<uint2*>(base + dt * 32 + 8 * b4 + 4 * h) = ow;
        }
}

extern "C" void kernel_launch(void* const* d_in, const int* in_sizes, int n_in,
                              void* d_out, int out_size, void* d_ws, size_t ws_size,
                              hipStream_t stream) {
    const float* x      = (const float*)d_in[0];
    const float* w_qkv  = (const float*)d_in[1];
    const float* w_proj = (const float*)d_in[2];
    float* out = (float*)d_out;

    const size_t HELEMS = (size_t)B_ * NH_ * T_ * HD_;   // 4,194,304
    unsigned short* Qb   = (unsigned short*)d_ws;
    unsigned short* Kb   = Qb + HELEMS;
    unsigned short* Vraw = Kb + HELEMS;       // row-major V; later reused as Yb
    unsigned short* Yb   = Vraw;              //   (V dead after post)
    unsigned short* Xb   = Vraw + HELEMS;     // bf16 x; later reused as Vt
    unsigned short* Vt   = Xb;                //   (x dead after qkv_gemm)
    unsigned short* Wqt  = Xb + HELEMS;       // 3072x1024; Wpt aliases
    unsigned short* Wpt  = Wqt;               //   (Wq dead after qkv_gemm)
                                              // total 38 MB

    prep<<<2816, 256, 0, stream>>>(x, w_qkv, Xb, Wqt);
    qkv_gemm_mfma<<<768, 256, 0, stream>>>(Xb, Wqt, Qb, Kb, Vraw);
    post<<<1280, 256, 0, stream>>>(Vraw, Vt, w_proj, Wpt);
    attn_mfma<<<512, 256, 0, stream>>>(Qb, Kb, Vt, Yb);
    proj_gemm_mfma<<<dim3(8, 64), 256, 0, stream>>>(Yb, Wpt, out);
}

// Round 19
// 111.906 us; speedup vs baseline: 1.1461x; 1.1461x over previous
//
#include <hip/hip_runtime.h>
#include <hip/hip_bf16.h>

#define B_ 2
#define T_ 2048
#define C_ 1024
#define NH_ 16
#define HD_ 64

using bf16 = __hip_bfloat16;
typedef __attribute__((ext_vector_type(8))) short bf16x8;
typedef __attribute__((ext_vector_type(4))) float f32x4;

__device__ __forceinline__ float bf2f(unsigned short u) {
    union { unsigned int i; float f; } v;
    v.i = ((unsigned int)u) << 16;
    return v.f;
}
__device__ __forceinline__ unsigned short f2bf(float f) {
    union { float f; unsigned int u; } v;
    v.f = f;
    unsigned int r = v.u + 0x7fffu + ((v.u >> 16) & 1u);  // RNE
    return (unsigned short)(r >> 16);
}
// pack 2 fp32 -> 2 bf16 (RNE) in one instruction; lo in bits 0-15
__device__ __forceinline__ unsigned int cvt_pk_bf16(float lo, float hi) {
    unsigned int r;
    asm("v_cvt_pk_bf16_f32 %0, %1, %2" : "=v"(r) : "v"(lo), "v"(hi));
    return r;
}
__device__ __forceinline__ void gld_lds16(const void* g, void* l) {
    __builtin_amdgcn_global_load_lds(
        (__attribute__((address_space(1))) void*)g,
        (__attribute__((address_space(3))) void*)l, 16, 0, 0);
}

// ---------------------------------------------------------------------------
// prep: cast_bf16(x) [0..2047] + transpose_cast(w_qkv) [2048..2815]
//       + transpose_cast(w_proj) [2816..3071]  (Wpt de-aliased -> can run
//       before qkv_gemm; post shrinks to transpose_v only).
// ---------------------------------------------------------------------------
__global__ __launch_bounds__(256) void prep(
    const float* __restrict__ X, const float* __restrict__ Wq,
    const float* __restrict__ Wp,
    unsigned short* __restrict__ Xb, unsigned short* __restrict__ Wqt,
    unsigned short* __restrict__ Wpt) {
    __shared__ short S[64][72];
    const int b = blockIdx.x;
    const int t = threadIdx.x;
    if (b < 2048) {
        int i = (b * 256 + t) * 8;
        float4 f0 = *reinterpret_cast<const float4*>(&X[i]);
        float4 f1 = *reinterpret_cast<const float4*>(&X[i + 4]);
        union { unsigned short s[8]; uint4 v; } o;
        o.s[0] = f2bf(f0.x); o.s[1] = f2bf(f0.y); o.s[2] = f2bf(f0.z); o.s[3] = f2bf(f0.w);
        o.s[4] = f2bf(f1.x); o.s[5] = f2bf(f1.y); o.s[6] = f2bf(f1.z); o.s[7] = f2bf(f1.w);
        *reinterpret_cast<uint4*>(&Xb[i]) = o.v;
        return;
    }
    const int lr = t >> 2, lc = (t & 3) * 16;
    const float* src;
    unsigned short* dstbase;
    int NN, KK, n0, k0;
    if (b < 2816) {
        const int idx = b - 2048;            // 0..767 = 48 x 16
        n0 = (idx % 48) * 64; k0 = (idx / 48) * 64;
        NN = 3 * C_; KK = C_;
        src = &Wq[(size_t)(k0 + lr) * NN + n0 + lc];
        dstbase = Wqt;
    } else {
        const int idx = b - 2816;            // 0..255 = 16 x 16
        n0 = (idx & 15) * 64; k0 = (idx >> 4) * 64;
        NN = C_; KK = C_;
        src = &Wp[(size_t)(k0 + lr) * NN + n0 + lc];
        dstbase = Wpt;
    }
    #pragma unroll
    for (int j4 = 0; j4 < 4; ++j4) {
        float4 f = *reinterpret_cast<const float4*>(src + j4 * 4);
        S[lc + j4 * 4 + 0][lr] = (short)f2bf(f.x);
        S[lc + j4 * 4 + 1][lr] = (short)f2bf(f.y);
        S[lc + j4 * 4 + 2][lr] = (short)f2bf(f.z);
        S[lc + j4 * 4 + 3][lr] = (short)f2bf(f.w);
    }
    __syncthreads();
    union { unsigned short s[16]; uint4 v[2]; } o;
    #pragma unroll
    for (int j = 0; j < 16; ++j) o.s[j] = (unsigned short)S[lr][lc + j];
    unsigned short* dst = &dstbase[(size_t)(n0 + lr) * KK + k0 + lc];
    *reinterpret_cast<uint4*>(dst)     = o.v[0];
    *reinterpret_cast<uint4*>(dst + 8) = o.v[1];
}

// ---------------------------------------------------------------------------
// post: transpose_v only. V[bh][T][HD] -> Vt[bh][HD][T], 64x64 tiles.
// ---------------------------------------------------------------------------
__global__ __launch_bounds__(256) void post(
    const unsigned short* __restrict__ V, unsigned short* __restrict__ Vt) {
    __shared__ short S[64][72];
    const int b = blockIdx.x;
    const int t = threadIdx.x;
    const int lr = t >> 2, lc = (t & 3) * 16;
    const int bh = b >> 5, t0 = (b & 31) * 64;
    const unsigned short* src = V + ((size_t)bh * T_ + t0 + lr) * HD_ + lc;
    union { uint4 v[2]; unsigned short s[16]; } u;
    u.v[0] = *reinterpret_cast<const uint4*>(src);
    u.v[1] = *reinterpret_cast<const uint4*>(src + 8);
    #pragma unroll
    for (int j = 0; j < 16; ++j) S[lc + j][lr] = (short)u.s[j];
    __syncthreads();
    union { unsigned short s[16]; uint4 v[2]; } o;
    #pragma unroll
    for (int j = 0; j < 16; ++j) o.s[j] = (unsigned short)S[lr][lc + j];
    unsigned short* dst = Vt + ((size_t)bh * HD_ + lr) * T_ + t0 + lc;
    *reinterpret_cast<uint4*>(dst)     = o.v[0];
    *reinterpret_cast<uint4*>(dst + 8) = o.v[1];
}

// ---------------------------------------------------------------------------
// QKV GEMM, bf16 MFMA, dbuf single-barrier. Q pre-scaled by log2e/8;
// XCD swizzle (768 = 8x96).
// ---------------------------------------------------------------------------
__global__ __launch_bounds__(256) void qkv_gemm_mfma(
    const unsigned short* __restrict__ A, const unsigned short* __restrict__ Bt,
    unsigned short* __restrict__ Qb, unsigned short* __restrict__ Kb,
    unsigned short* __restrict__ Vb) {
    __shared__ short As[2][128 * 32];
    __shared__ short Bs[2][128 * 32];
    const int t = threadIdx.x;
    const int wid = t >> 6, lane = t & 63;
    const int wm = wid >> 1, wn = wid & 1;
    const int c = lane & 15, g = lane >> 4;
    const int dd = blockIdx.x;
    const int w  = (dd & 7) * 96 + (dd >> 3);
    const int m0 = (w / 24) * 128, n0 = (w % 24) * 128;
    const int K = C_;
    const int srow = t >> 2, skk = (t & 3) * 8;

    f32x4 acc[4][4];
    #pragma unroll
    for (int i = 0; i < 4; ++i)
        #pragma unroll
        for (int j = 0; j < 4; ++j) acc[i][j] = (f32x4){0.f, 0.f, 0.f, 0.f};

    gld_lds16(&A[(size_t)(m0 + srow) * K + skk],       As[0] + t * 8);
    gld_lds16(&A[(size_t)(m0 + 64 + srow) * K + skk],  As[0] + 2048 + t * 8);
    gld_lds16(&Bt[(size_t)(n0 + srow) * K + skk],      Bs[0] + t * 8);
    gld_lds16(&Bt[(size_t)(n0 + 64 + srow) * K + skk], Bs[0] + 2048 + t * 8);

    #pragma unroll 1
    for (int kt = 0; kt < 32; ++kt) {
        const int cur = kt & 1;
        __syncthreads();
        if (kt < 31) {
            const int k0 = (kt + 1) * 32;
            gld_lds16(&A[(size_t)(m0 + srow) * K + k0 + skk],       As[cur ^ 1] + t * 8);
            gld_lds16(&A[(size_t)(m0 + 64 + srow) * K + k0 + skk],  As[cur ^ 1] + 2048 + t * 8);
            gld_lds16(&Bt[(size_t)(n0 + srow) * K + k0 + skk],      Bs[cur ^ 1] + t * 8);
            gld_lds16(&Bt[(size_t)(n0 + 64 + srow) * K + k0 + skk], Bs[cur ^ 1] + 2048 + t * 8);
        }
        bf16x8 af[4], bfv[4];
        #pragma unroll
        for (int mi = 0; mi < 4; ++mi)
            af[mi] = *reinterpret_cast<const bf16x8*>(&As[cur][(wm * 64 + mi * 16 + c) * 32 + g * 8]);
        #pragma unroll
        for (int ni = 0; ni < 4; ++ni)
            bfv[ni] = *reinterpret_cast<const bf16x8*>(&Bs[cur][(wn * 64 + ni * 16 + c) * 32 + g * 8]);
        #pragma unroll
        for (int mi = 0; mi < 4; ++mi)
            #pragma unroll
            for (int ni = 0; ni < 4; ++ni)
                acc[mi][ni] = __builtin_amdgcn_mfma_f32_16x16x32_bf16(af[mi], bfv[ni], acc[mi][ni], 0, 0, 0);
    }

    const int nbase = n0 + wn * 64;
    const int which = nbase >> 10;
    const int h     = (nbase >> 6) & (NH_ - 1);
    // Q scale: 1/sqrt(HD) * log2(e)  (attn softmax runs in exp2 domain)
    const float scale = (which == 0) ? 0.125f * 1.44269504f : 1.0f;
    unsigned short* dst = (which == 0) ? Qb : ((which == 1) ? Kb : Vb);
    #pragma unroll
    for (int mi = 0; mi < 4; ++mi)
        #pragma unroll
        for (int r = 0; r < 4; ++r) {
            const int m = m0 + wm * 64 + mi * 16 + 4 * g + r;
            const int bb = m >> 11, tq = m & (T_ - 1);
            unsigned short* p = dst + ((size_t)((bb << 4) | h) * T_ + tq) * HD_;
            #pragma unroll
            for (int ni = 0; ni < 4; ++ni)
                p[ni * 16 + c] = f2bf(acc[mi][ni][r] * scale);
        }
}

// ---------------------------------------------------------------------------
// Projection GEMM, bf16 MFMA, 64x128 tile, dbuf single-barrier loop.
// ---------------------------------------------------------------------------
__global__ __launch_bounds__(256) void proj_gemm_mfma(
    const unsigned short* __restrict__ A, const unsigned short* __restrict__ Bt,
    float* __restrict__ Out) {
    __shared__ short As[2][64 * 32];
    __shared__ short Bs[2][128 * 32];
    const int t = threadIdx.x;
    const int wid = t >> 6, lane = t & 63;
    const int wm = wid >> 1, wn = wid & 1;
    const int c = lane & 15, g = lane >> 4;
    const int m0 = blockIdx.y * 64, n0 = blockIdx.x * 128;
    const int K = C_;
    const int srow = t >> 2, skk = (t & 3) * 8;

    f32x4 acc[2][4];
    #pragma unroll
    for (int i = 0; i < 2; ++i)
        #pragma unroll
        for (int j = 0; j < 4; ++j) acc[i][j] = (f32x4){0.f, 0.f, 0.f, 0.f};

    gld_lds16(&A[(size_t)(m0 + srow) * K + skk],       As[0] + t * 8);
    gld_lds16(&Bt[(size_t)(n0 + srow) * K + skk],      Bs[0] + t * 8);
    gld_lds16(&Bt[(size_t)(n0 + 64 + srow) * K + skk], Bs[0] + 2048 + t * 8);

    #pragma unroll 1
    for (int kt = 0; kt < 32; ++kt) {
        const int cur = kt & 1;
        __syncthreads();
        if (kt < 31) {
            const int k0 = (kt + 1) * 32;
            gld_lds16(&A[(size_t)(m0 + srow) * K + k0 + skk],       As[cur ^ 1] + t * 8);
            gld_lds16(&Bt[(size_t)(n0 + srow) * K + k0 + skk],      Bs[cur ^ 1] + t * 8);
            gld_lds16(&Bt[(size_t)(n0 + 64 + srow) * K + k0 + skk], Bs[cur ^ 1] + 2048 + t * 8);
        }
        bf16x8 af[2], bfv[4];
        #pragma unroll
        for (int mi = 0; mi < 2; ++mi)
            af[mi] = *reinterpret_cast<const bf16x8*>(&As[cur][(wm * 32 + mi * 16 + c) * 32 + g * 8]);
        #pragma unroll
        for (int ni = 0; ni < 4; ++ni)
            bfv[ni] = *reinterpret_cast<const bf16x8*>(&Bs[cur][(wn * 64 + ni * 16 + c) * 32 + g * 8]);
        #pragma unroll
        for (int mi = 0; mi < 2; ++mi)
            #pragma unroll
            for (int ni = 0; ni < 4; ++ni)
                acc[mi][ni] = __builtin_amdgcn_mfma_f32_16x16x32_bf16(af[mi], bfv[ni], acc[mi][ni], 0, 0, 0);
    }

    #pragma unroll
    for (int mi = 0; mi < 2; ++mi)
        #pragma unroll
        for (int r = 0; r < 4; ++r) {
            const int m = m0 + wm * 32 + mi * 16 + 4 * g + r;
            float* p = Out + (size_t)m * C_ + n0 + wn * 64;
            #pragma unroll
            for (int ni = 0; ni < 4; ++ni)
                p[ni * 16 + c] = acc[mi][ni][r];
        }
}

// ---------------------------------------------------------------------------
// Flash attention (best-known r14/r17 structure). MFMA bf16 16x16x32,
// swapped QK^T, j-permuted PV (zero P LDS round-trip), static-max exp2.
// 512 threads / 8 waves: waves 0-3 own q-tile A (2u), waves 4-7 own B (2u+1);
// ONE shared dbuf K/V staging stream, one barrier/iter. 2 blocks/CU,
// 16 waves/CU (the 32x32 shape halves wave count -> worse; r18 measured).
// Cross-CU balance: blocks (d, d+256) get complementary u. bh%8 = XCD.
// ---------------------------------------------------------------------------
__global__ __launch_bounds__(512) void attn_mfma(
    const unsigned short* __restrict__ Qb, const unsigned short* __restrict__ Kb,
    const unsigned short* __restrict__ Vt_g, unsigned short* __restrict__ Yu) {
    __shared__ short Ks[2][64][72];     // [buf][j][d]
    __shared__ short Vt[2][64][72];     // [buf][d][slot]  (j-permuted columns)

    const int t    = threadIdx.x;
    const int wid  = t >> 6;            // 0..7
    const int lane = t & 63;
    const int c    = lane & 15;
    const int g    = lane >> 4;

    // --- block decode ---
    const int d   = blockIdx.x;              // 0..511
    const int xcd = d & 7;
    const int tt  = d >> 3;                  // 0..63
    const int up  = tt & 15;
    const int k2  = tt >> 4;                 // 0..3
    const int bh  = (k2 << 3) | xcd;
    const int u   = (k2 & 2) ? (15 - up) : up;
    const int qtB = 2 * u + 1;
    const int myqt = (wid < 4) ? (2 * u) : qtB;

    const int bb = bh >> 4, h = bh & (NH_ - 1);
    const int qw0 = (wid & 3) * 16;
    const int q0  = myqt * 64;

    const unsigned short* Qh  = Qb   + (size_t)bh * T_ * HD_;
    const unsigned short* Kh  = Kb   + (size_t)bh * T_ * HD_;
    const unsigned short* VTh = Vt_g + (size_t)bh * HD_ * T_;

    // staging: 512 threads, 16B K + 16B V each
    const int srow = t >> 3, scol = (t & 7) * 8;
    // V slot targets for the two 4-runs (per-thread constants)
    const int jA = scol, jB = scol + 4;
    const int slotA = 32 * (jA >> 5) + 8 * ((jA >> 2) & 3) + 4 * ((jA >> 4) & 1);
    const int slotB = 32 * (jB >> 5) + 8 * ((jB >> 2) & 3) + 4 * ((jB >> 4) & 1);

    // Q fragments in registers (pre-scaled by log2e/8 in qkv epilogue)
    bf16x8 qf0, qf1;
    {
        const unsigned short* qs = Qh + (size_t)(q0 + qw0 + c) * HD_ + g * 8;
        qf0 = *reinterpret_cast<const bf16x8*>(qs);
        qf1 = *reinterpret_cast<const bf16x8*>(qs + 32);
    }

    float l_run = 0.f;
    f32x4 yacc[4];
    #pragma unroll
    for (int nt = 0; nt < 4; ++nt) yacc[nt] = (f32x4){0.f, 0.f, 0.f, 0.f};

    // prologue: load tile 0 into regs
    uint4 kv, vv;
    {
        kv = *reinterpret_cast<const uint4*>(&Kh[(size_t)srow * HD_ + scol]);
        vv = *reinterpret_cast<const uint4*>(&VTh[(size_t)srow * T_ + scol]);
    }

    #pragma unroll 1
    for (int kt = 0; kt <= qtB; ++kt) {
        const int cur = kt & 1;
        *reinterpret_cast<uint4*>(&Ks[cur][srow][scol]) = kv;
        *reinterpret_cast<uint2*>(&Vt[cur][srow][slotA]) = make_uint2(vv.x, vv.y);
        *reinterpret_cast<uint2*>(&Vt[cur][srow][slotB]) = make_uint2(vv.z, vv.w);
        __syncthreads();            // staging visible; gates next write of buf^1

        if (kt < qtB) {             // issue next tile's loads; land during compute
            const int j1 = (kt + 1) * 64;
            kv = *reinterpret_cast<const uint4*>(&Kh[(size_t)(j1 + srow) * HD_ + scol]);
            vv = *reinterpret_cast<const uint4*>(&VTh[(size_t)srow * T_ + j1 + scol]);
        }

        if (kt <= myqt) {
            // ---- S^T = K Q^T : 8 MFMA. lane holds S[q=qw0+c][j=nt*16+4g+r]
            f32x4 sacc[4];
            #pragma unroll
            for (int nt = 0; nt < 4; ++nt) sacc[nt] = (f32x4){0.f, 0.f, 0.f, 0.f};
            __builtin_amdgcn_s_setprio(1);
            #pragma unroll
            for (int kk = 0; kk < 2; ++kk) {
                const bf16x8 qf = kk ? qf1 : qf0;
                #pragma unroll
                for (int nt = 0; nt < 4; ++nt) {
                    bf16x8 kf = *reinterpret_cast<const bf16x8*>(&Ks[cur][nt * 16 + c][kk * 32 + g * 8]);
                    sacc[nt] = __builtin_amdgcn_mfma_f32_16x16x32_bf16(kf, qf, sacc[nt], 0, 0, 0);
                }
            }
            __builtin_amdgcn_s_setprio(0);

            // ---- static-max softmax (exp2 domain, no cross-lane ops) ----
            const bool diag = (kt == myqt);
            float p[4][4];
            float lsum = 0.f;
            #pragma unroll
            for (int nt = 0; nt < 4; ++nt)
                #pragma unroll
                for (int r = 0; r < 4; ++r) {
                    float s = sacc[nt][r];
                    if (diag && (nt * 16 + 4 * g + r > qw0 + c)) s = -1e30f;
                    float pv = exp2f(s);
                    p[nt][r] = pv;
                    lsum += pv;
                }
            l_run += lsum;                  // per-lane partial

            // pack P -> own A-frag words (j-permutation; no LDS round-trip)
            unsigned int pk[8];
            #pragma unroll
            for (int nt = 0; nt < 4; ++nt) {
                pk[2 * nt]     = cvt_pk_bf16(p[nt][0], p[nt][1]);
                pk[2 * nt + 1] = cvt_pk_bf16(p[nt][2], p[nt][3]);
            }

            // ---- y += P V : 8 MFMA (A = own pk words; B = permuted Vt) ----
            __builtin_amdgcn_s_setprio(1);
            #pragma unroll
            for (int kk = 0; kk < 2; ++kk) {
                union { unsigned int w[4]; bf16x8 v; } pa;
                pa.w[0] = pk[4 * kk + 0]; pa.w[1] = pk[4 * kk + 1];
                pa.w[2] = pk[4 * kk + 2]; pa.w[3] = pk[4 * kk + 3];
                #pragma unroll
                for (int nt = 0; nt < 4; ++nt) {
                    bf16x8 vb = *reinterpret_cast<const bf16x8*>(&Vt[cur][nt * 16 + c][kk * 32 + g * 8]);
                    yacc[nt] = __builtin_amdgcn_mfma_f32_16x16x32_bf16(pa.v, vb, yacc[nt], 0, 0, 0);
                }
            }
            __builtin_amdgcn_s_setprio(0);
        }
    }

    // ---- epilogue: finish l (2 shfl), broadcast inv to PV layout, store ----
    float lf = l_run;
    lf += __shfl_xor(lf, 16, 64);
    lf += __shfl_xor(lf, 32, 64);
    const float inv = 1.0f / lf;              // for row q = qw0 + c
    const int ii = __float_as_int(inv);
    float invr[4];
    #pragma unroll
    for (int r = 0; r < 4; ++r)
        invr[r] = __int_as_float(__builtin_amdgcn_ds_bpermute((4 * g + r) * 4, ii));
    #pragma unroll
    for (int r = 0; r < 4; ++r) {
        const size_t row = (size_t)(bb * T_ + q0 + qw0 + 4 * g + r);
        #pragma unroll
        for (int nt = 0; nt < 4; ++nt) {
            const int col = h * HD_ + 16 * nt + c;
            Yu[row * C_ + col] = f2bf(yacc[nt][r] * invr[r]);
        }
    }
}

extern "C" void kernel_launch(void* const* d_in, const int* in_sizes, int n_in,
                              void* d_out, int out_size, void* d_ws, size_t ws_size,
                              hipStream_t stream) {
    const float* x      = (const float*)d_in[0];
    const float* w_qkv  = (const float*)d_in[1];
    const float* w_proj = (const float*)d_in[2];
    float* out = (float*)d_out;

    const size_t HELEMS = (size_t)B_ * NH_ * T_ * HD_;   // 4,194,304
    unsigned short* Qb   = (unsigned short*)d_ws;
    unsigned short* Kb   = Qb + HELEMS;
    unsigned short* Vraw = Kb + HELEMS;       // row-major V; later reused as Yb
    unsigned short* Yb   = Vraw;              //   (V dead after post)
    unsigned short* Xb   = Vraw + HELEMS;     // bf16 x; later reused as Vt
    unsigned short* Vt   = Xb;                //   (x dead after qkv_gemm)
    unsigned short* Wqt  = Xb + HELEMS;       // 3072x1024 bf16 (6MB)
    unsigned short* Wpt  = Wqt + (size_t)3 * C_ * C_;    // own 1024x1024 (2MB)
                                              // total 40 MB (ws >= 48.5 proven)

    prep<<<3072, 256, 0, stream>>>(x, w_qkv, w_proj, Xb, Wqt, Wpt);
    qkv_gemm_mfma<<<768, 256, 0, stream>>>(Xb, Wqt, Qb, Kb, Vraw);
    post<<<1024, 256, 0, stream>>>(Vraw, Vt);
    attn_mfma<<<512, 512, 0, stream>>>(Qb, Kb, Vt, Yb);
    proj_gemm_mfma<<<dim3(8, 64), 256, 0, stream>>>(Yb, Wpt, out);
}

// Round 20
// 107.854 us; speedup vs baseline: 1.1891x; 1.0376x over previous
//
#include <hip/hip_runtime.h>
#include <hip/hip_bf16.h>

#define B_ 2
#define T_ 2048
#define C_ 1024
#define NH_ 16
#define HD_ 64

using bf16 = __hip_bfloat16;
typedef __attribute__((ext_vector_type(8))) short bf16x8;
typedef __attribute__((ext_vector_type(4))) float f32x4;

__device__ __forceinline__ float bf2f(unsigned short u) {
    union { unsigned int i; float f; } v;
    v.i = ((unsigned int)u) << 16;
    return v.f;
}
__device__ __forceinline__ unsigned short f2bf(float f) {
    union { float f; unsigned int u; } v;
    v.f = f;
    unsigned int r = v.u + 0x7fffu + ((v.u >> 16) & 1u);  // RNE
    return (unsigned short)(r >> 16);
}
// pack 2 fp32 -> 2 bf16 (RNE) in one instruction; lo in bits 0-15
__device__ __forceinline__ unsigned int cvt_pk_bf16(float lo, float hi) {
    unsigned int r;
    asm("v_cvt_pk_bf16_f32 %0, %1, %2" : "=v"(r) : "v"(lo), "v"(hi));
    return r;
}
__device__ __forceinline__ void gld_lds16(const void* g, void* l) {
    __builtin_amdgcn_global_load_lds(
        (__attribute__((address_space(1))) void*)g,
        (__attribute__((address_space(3))) void*)l, 16, 0, 0);
}

// ---------------------------------------------------------------------------
// prep: cast_bf16(x) [0..2047] + transpose_cast(w_qkv) [2048..2815]
//       + transpose_cast(w_proj) [2816..3071].
// ---------------------------------------------------------------------------
__global__ __launch_bounds__(256) void prep(
    const float* __restrict__ X, const float* __restrict__ Wq,
    const float* __restrict__ Wp,
    unsigned short* __restrict__ Xb, unsigned short* __restrict__ Wqt,
    unsigned short* __restrict__ Wpt) {
    __shared__ short S[64][72];
    const int b = blockIdx.x;
    const int t = threadIdx.x;
    if (b < 2048) {
        int i = (b * 256 + t) * 8;
        float4 f0 = *reinterpret_cast<const float4*>(&X[i]);
        float4 f1 = *reinterpret_cast<const float4*>(&X[i + 4]);
        union { unsigned short s[8]; uint4 v; } o;
        o.s[0] = f2bf(f0.x); o.s[1] = f2bf(f0.y); o.s[2] = f2bf(f0.z); o.s[3] = f2bf(f0.w);
        o.s[4] = f2bf(f1.x); o.s[5] = f2bf(f1.y); o.s[6] = f2bf(f1.z); o.s[7] = f2bf(f1.w);
        *reinterpret_cast<uint4*>(&Xb[i]) = o.v;
        return;
    }
    const int lr = t >> 2, lc = (t & 3) * 16;
    const float* src;
    unsigned short* dstbase;
    int NN, KK, n0, k0;
    if (b < 2816) {
        const int idx = b - 2048;            // 0..767 = 48 x 16
        n0 = (idx % 48) * 64; k0 = (idx / 48) * 64;
        NN = 3 * C_; KK = C_;
        src = &Wq[(size_t)(k0 + lr) * NN + n0 + lc];
        dstbase = Wqt;
    } else {
        const int idx = b - 2816;            // 0..255 = 16 x 16
        n0 = (idx & 15) * 64; k0 = (idx >> 4) * 64;
        NN = C_; KK = C_;
        src = &Wp[(size_t)(k0 + lr) * NN + n0 + lc];
        dstbase = Wpt;
    }
    #pragma unroll
    for (int j4 = 0; j4 < 4; ++j4) {
        float4 f = *reinterpret_cast<const float4*>(src + j4 * 4);
        S[lc + j4 * 4 + 0][lr] = (short)f2bf(f.x);
        S[lc + j4 * 4 + 1][lr] = (short)f2bf(f.y);
        S[lc + j4 * 4 + 2][lr] = (short)f2bf(f.z);
        S[lc + j4 * 4 + 3][lr] = (short)f2bf(f.w);
    }
    __syncthreads();
    union { unsigned short s[16]; uint4 v[2]; } o;
    #pragma unroll
    for (int j = 0; j < 16; ++j) o.s[j] = (unsigned short)S[lr][lc + j];
    unsigned short* dst = &dstbase[(size_t)(n0 + lr) * KK + k0 + lc];
    *reinterpret_cast<uint4*>(dst)     = o.v[0];
    *reinterpret_cast<uint4*>(dst + 8) = o.v[1];
}

// ---------------------------------------------------------------------------
// post: transpose_v only. V[bh][T][HD] -> Vt[bh][HD][T], 64x64 tiles.
// ---------------------------------------------------------------------------
__global__ __launch_bounds__(256) void post(
    const unsigned short* __restrict__ V, unsigned short* __restrict__ Vt) {
    __shared__ short S[64][72];
    const int b = blockIdx.x;
    const int t = threadIdx.x;
    const int lr = t >> 2, lc = (t & 3) * 16;
    const int bh = b >> 5, t0 = (b & 31) * 64;
    const unsigned short* src = V + ((size_t)bh * T_ + t0 + lr) * HD_ + lc;
    union { uint4 v[2]; unsigned short s[16]; } u;
    u.v[0] = *reinterpret_cast<const uint4*>(src);
    u.v[1] = *reinterpret_cast<const uint4*>(src + 8);
    #pragma unroll
    for (int j = 0; j < 16; ++j) S[lc + j][lr] = (short)u.s[j];
    __syncthreads();
    union { unsigned short s[16]; uint4 v[2]; } o;
    #pragma unroll
    for (int j = 0; j < 16; ++j) o.s[j] = (unsigned short)S[lr][lc + j];
    unsigned short* dst = Vt + ((size_t)bh * HD_ + lr) * T_ + t0 + lc;
    *reinterpret_cast<uint4*>(dst)     = o.v[0];
    *reinterpret_cast<uint4*>(dst + 8) = o.v[1];
}

// ---------------------------------------------------------------------------
// QKV GEMM, bf16 MFMA, dbuf single-barrier. Q pre-scaled by log2e/8;
// XCD swizzle (768 = 8x96).
// ---------------------------------------------------------------------------
__global__ __launch_bounds__(256) void qkv_gemm_mfma(
    const unsigned short* __restrict__ A, const unsigned short* __restrict__ Bt,
    unsigned short* __restrict__ Qb, unsigned short* __restrict__ Kb,
    unsigned short* __restrict__ Vb) {
    __shared__ short As[2][128 * 32];
    __shared__ short Bs[2][128 * 32];
    const int t = threadIdx.x;
    const int wid = t >> 6, lane = t & 63;
    const int wm = wid >> 1, wn = wid & 1;
    const int c = lane & 15, g = lane >> 4;
    const int dd = blockIdx.x;
    const int w  = (dd & 7) * 96 + (dd >> 3);
    const int m0 = (w / 24) * 128, n0 = (w % 24) * 128;
    const int K = C_;
    const int srow = t >> 2, skk = (t & 3) * 8;

    f32x4 acc[4][4];
    #pragma unroll
    for (int i = 0; i < 4; ++i)
        #pragma unroll
        for (int j = 0; j < 4; ++j) acc[i][j] = (f32x4){0.f, 0.f, 0.f, 0.f};

    gld_lds16(&A[(size_t)(m0 + srow) * K + skk],       As[0] + t * 8);
    gld_lds16(&A[(size_t)(m0 + 64 + srow) * K + skk],  As[0] + 2048 + t * 8);
    gld_lds16(&Bt[(size_t)(n0 + srow) * K + skk],      Bs[0] + t * 8);
    gld_lds16(&Bt[(size_t)(n0 + 64 + srow) * K + skk], Bs[0] + 2048 + t * 8);

    #pragma unroll 1
    for (int kt = 0; kt < 32; ++kt) {
        const int cur = kt & 1;
        __syncthreads();
        if (kt < 31) {
            const int k0 = (kt + 1) * 32;
            gld_lds16(&A[(size_t)(m0 + srow) * K + k0 + skk],       As[cur ^ 1] + t * 8);
            gld_lds16(&A[(size_t)(m0 + 64 + srow) * K + k0 + skk],  As[cur ^ 1] + 2048 + t * 8);
            gld_lds16(&Bt[(size_t)(n0 + srow) * K + k0 + skk],      Bs[cur ^ 1] + t * 8);
            gld_lds16(&Bt[(size_t)(n0 + 64 + srow) * K + k0 + skk], Bs[cur ^ 1] + 2048 + t * 8);
        }
        bf16x8 af[4], bfv[4];
        #pragma unroll
        for (int mi = 0; mi < 4; ++mi)
            af[mi] = *reinterpret_cast<const bf16x8*>(&As[cur][(wm * 64 + mi * 16 + c) * 32 + g * 8]);
        #pragma unroll
        for (int ni = 0; ni < 4; ++ni)
            bfv[ni] = *reinterpret_cast<const bf16x8*>(&Bs[cur][(wn * 64 + ni * 16 + c) * 32 + g * 8]);
        #pragma unroll
        for (int mi = 0; mi < 4; ++mi)
            #pragma unroll
            for (int ni = 0; ni < 4; ++ni)
                acc[mi][ni] = __builtin_amdgcn_mfma_f32_16x16x32_bf16(af[mi], bfv[ni], acc[mi][ni], 0, 0, 0);
    }

    const int nbase = n0 + wn * 64;
    const int which = nbase >> 10;
    const int h     = (nbase >> 6) & (NH_ - 1);
    // Q scale: 1/sqrt(HD) * log2(e)  (attn softmax runs in exp2 domain)
    const float scale = (which == 0) ? 0.125f * 1.44269504f : 1.0f;
    unsigned short* dst = (which == 0) ? Qb : ((which == 1) ? Kb : Vb);
    #pragma unroll
    for (int mi = 0; mi < 4; ++mi)
        #pragma unroll
        for (int r = 0; r < 4; ++r) {
            const int m = m0 + wm * 64 + mi * 16 + 4 * g + r;
            const int bb = m >> 11, tq = m & (T_ - 1);
            unsigned short* p = dst + ((size_t)((bb << 4) | h) * T_ + tq) * HD_;
            #pragma unroll
            for (int ni = 0; ni < 4; ++ni)
                p[ni * 16 + c] = f2bf(acc[mi][ni][r] * scale);
        }
}

// ---------------------------------------------------------------------------
// Projection GEMM, bf16 MFMA, 64x128 tile, dbuf single-barrier loop.
// Round-20: XCD swizzle (512 = 8 XCDs x 64): w = (d&7)*64 + d/8;
// tm = w>>3 (0..63), tn = w&7. Each XCD: 8 A-panels (1MB) + full Wpt (2MB)
// = 3MB working set < 4MB XCD L2.
// ---------------------------------------------------------------------------
__global__ __launch_bounds__(256) void proj_gemm_mfma(
    const unsigned short* __restrict__ A, const unsigned short* __restrict__ Bt,
    float* __restrict__ Out) {
    __shared__ short As[2][64 * 32];
    __shared__ short Bs[2][128 * 32];
    const int t = threadIdx.x;
    const int wid = t >> 6, lane = t & 63;
    const int wm = wid >> 1, wn = wid & 1;
    const int c = lane & 15, g = lane >> 4;
    const int dd = blockIdx.x;
    const int w  = (dd & 7) * 64 + (dd >> 3);
    const int m0 = (w >> 3) * 64, n0 = (w & 7) * 128;
    const int K = C_;
    const int srow = t >> 2, skk = (t & 3) * 8;

    f32x4 acc[2][4];
    #pragma unroll
    for (int i = 0; i < 2; ++i)
        #pragma unroll
        for (int j = 0; j < 4; ++j) acc[i][j] = (f32x4){0.f, 0.f, 0.f, 0.f};

    gld_lds16(&A[(size_t)(m0 + srow) * K + skk],       As[0] + t * 8);
    gld_lds16(&Bt[(size_t)(n0 + srow) * K + skk],      Bs[0] + t * 8);
    gld_lds16(&Bt[(size_t)(n0 + 64 + srow) * K + skk], Bs[0] + 2048 + t * 8);

    #pragma unroll 1
    for (int kt = 0; kt < 32; ++kt) {
        const int cur = kt & 1;
        __syncthreads();
        if (kt < 31) {
            const int k0 = (kt + 1) * 32;
            gld_lds16(&A[(size_t)(m0 + srow) * K + k0 + skk],       As[cur ^ 1] + t * 8);
            gld_lds16(&Bt[(size_t)(n0 + srow) * K + k0 + skk],      Bs[cur ^ 1] + t * 8);
            gld_lds16(&Bt[(size_t)(n0 + 64 + srow) * K + k0 + skk], Bs[cur ^ 1] + 2048 + t * 8);
        }
        bf16x8 af[2], bfv[4];
        #pragma unroll
        for (int mi = 0; mi < 2; ++mi)
            af[mi] = *reinterpret_cast<const bf16x8*>(&As[cur][(wm * 32 + mi * 16 + c) * 32 + g * 8]);
        #pragma unroll
        for (int ni = 0; ni < 4; ++ni)
            bfv[ni] = *reinterpret_cast<const bf16x8*>(&Bs[cur][(wn * 64 + ni * 16 + c) * 32 + g * 8]);
        #pragma unroll
        for (int mi = 0; mi < 2; ++mi)
            #pragma unroll
            for (int ni = 0; ni < 4; ++ni)
                acc[mi][ni] = __builtin_amdgcn_mfma_f32_16x16x32_bf16(af[mi], bfv[ni], acc[mi][ni], 0, 0, 0);
    }

    #pragma unroll
    for (int mi = 0; mi < 2; ++mi)
        #pragma unroll
        for (int r = 0; r < 4; ++r) {
            const int m = m0 + wm * 32 + mi * 16 + 4 * g + r;
            float* p = Out + (size_t)m * C_ + n0 + wn * 64;
            #pragma unroll
            for (int ni = 0; ni < 4; ++ni)
                p[ni * 16 + c] = acc[mi][ni][r];
        }
}

// ---------------------------------------------------------------------------
// Flash attention (best-known r14/r17 structure). MFMA bf16 16x16x32,
// swapped QK^T, j-permuted PV (zero P LDS round-trip), static-max exp2.
// 512 threads / 8 waves: waves 0-3 own q-tile A (2u), waves 4-7 own B (2u+1);
// ONE shared dbuf K/V staging stream, one barrier/iter. 2 blocks/CU,
// 16 waves/CU. Cross-CU balance: blocks (d, d+256) complementary u; bh%8=XCD.
// ---------------------------------------------------------------------------
__global__ __launch_bounds__(512) void attn_mfma(
    const unsigned short* __restrict__ Qb, const unsigned short* __restrict__ Kb,
    const unsigned short* __restrict__ Vt_g, unsigned short* __restrict__ Yu) {
    __shared__ short Ks[2][64][72];     // [buf][j][d]
    __shared__ short Vt[2][64][72];     // [buf][d][slot]  (j-permuted columns)

    const int t    = threadIdx.x;
    const int wid  = t >> 6;            // 0..7
    const int lane = t & 63;
    const int c    = lane & 15;
    const int g    = lane >> 4;

    // --- block decode ---
    const int d   = blockIdx.x;              // 0..511
    const int xcd = d & 7;
    const int tt  = d >> 3;                  // 0..63
    const int up  = tt & 15;
    const int k2  = tt >> 4;                 // 0..3
    const int bh  = (k2 << 3) | xcd;
    const int u   = (k2 & 2) ? (15 - up) : up;
    const int qtB = 2 * u + 1;
    const int myqt = (wid < 4) ? (2 * u) : qtB;

    const int bb = bh >> 4, h = bh & (NH_ - 1);
    const int qw0 = (wid & 3) * 16;
    const int q0  = myqt * 64;

    const unsigned short* Qh  = Qb   + (size_t)bh * T_ * HD_;
    const unsigned short* Kh  = Kb   + (size_t)bh * T_ * HD_;
    const unsigned short* VTh = Vt_g + (size_t)bh * HD_ * T_;

    // staging: 512 threads, 16B K + 16B V each
    const int srow = t >> 3, scol = (t & 7) * 8;
    // V slot targets for the two 4-runs (per-thread constants)
    const int jA = scol, jB = scol + 4;
    const int slotA = 32 * (jA >> 5) + 8 * ((jA >> 2) & 3) + 4 * ((jA >> 4) & 1);
    const int slotB = 32 * (jB >> 5) + 8 * ((jB >> 2) & 3) + 4 * ((jB >> 4) & 1);

    // Q fragments in registers (pre-scaled by log2e/8 in qkv epilogue)
    bf16x8 qf0, qf1;
    {
        const unsigned short* qs = Qh + (size_t)(q0 + qw0 + c) * HD_ + g * 8;
        qf0 = *reinterpret_cast<const bf16x8*>(qs);
        qf1 = *reinterpret_cast<const bf16x8*>(qs + 32);
    }

    float l_run = 0.f;
    f32x4 yacc[4];
    #pragma unroll
    for (int nt = 0; nt < 4; ++nt) yacc[nt] = (f32x4){0.f, 0.f, 0.f, 0.f};

    // prologue: load tile 0 into regs
    uint4 kv, vv;
    {
        kv = *reinterpret_cast<const uint4*>(&Kh[(size_t)srow * HD_ + scol]);
        vv = *reinterpret_cast<const uint4*>(&VTh[(size_t)srow * T_ + scol]);
    }

    #pragma unroll 1
    for (int kt = 0; kt <= qtB; ++kt) {
        const int cur = kt & 1;
        *reinterpret_cast<uint4*>(&Ks[cur][srow][scol]) = kv;
        *reinterpret_cast<uint2*>(&Vt[cur][srow][slotA]) = make_uint2(vv.x, vv.y);
        *reinterpret_cast<uint2*>(&Vt[cur][srow][slotB]) = make_uint2(vv.z, vv.w);
        __syncthreads();            // staging visible; gates next write of buf^1

        if (kt < qtB) {             // issue next tile's loads; land during compute
            const int j1 = (kt + 1) * 64;
            kv = *reinterpret_cast<const uint4*>(&Kh[(size_t)(j1 + srow) * HD_ + scol]);
            vv = *reinterpret_cast<const uint4*>(&VTh[(size_t)srow * T_ + j1 + scol]);
        }

        if (kt <= myqt) {
            // ---- S^T = K Q^T : 8 MFMA. lane holds S[q=qw0+c][j=nt*16+4g+r]
            f32x4 sacc[4];
            #pragma unroll
            for (int nt = 0; nt < 4; ++nt) sacc[nt] = (f32x4){0.f, 0.f, 0.f, 0.f};
            __builtin_amdgcn_s_setprio(1);
            #pragma unroll
            for (int kk = 0; kk < 2; ++kk) {
                const bf16x8 qf = kk ? qf1 : qf0;
                #pragma unroll
                for (int nt = 0; nt < 4; ++nt) {
                    bf16x8 kf = *reinterpret_cast<const bf16x8*>(&Ks[cur][nt * 16 + c][kk * 32 + g * 8]);
                    sacc[nt] = __builtin_amdgcn_mfma_f32_16x16x32_bf16(kf, qf, sacc[nt], 0, 0, 0);
                }
            }
            __builtin_amdgcn_s_setprio(0);

            // ---- static-max softmax (exp2 domain, no cross-lane ops) ----
            const bool diag = (kt == myqt);
            float p[4][4];
            float lsum = 0.f;
            #pragma unroll
            for (int nt = 0; nt < 4; ++nt)
                #pragma unroll
                for (int r = 0; r < 4; ++r) {
                    float s = sacc[nt][r];
                    if (diag && (nt * 16 + 4 * g + r > qw0 + c)) s = -1e30f;
                    float pv = exp2f(s);
                    p[nt][r] = pv;
                    lsum += pv;
                }
            l_run += lsum;                  // per-lane partial

            // pack P -> own A-frag words (j-permutation; no LDS round-trip)
            unsigned int pk[8];
            #pragma unroll
            for (int nt = 0; nt < 4; ++nt) {
                pk[2 * nt]     = cvt_pk_bf16(p[nt][0], p[nt][1]);
                pk[2 * nt + 1] = cvt_pk_bf16(p[nt][2], p[nt][3]);
            }

            // ---- y += P V : 8 MFMA (A = own pk words; B = permuted Vt) ----
            __builtin_amdgcn_s_setprio(1);
            #pragma unroll
            for (int kk = 0; kk < 2; ++kk) {
                union { unsigned int w[4]; bf16x8 v; } pa;
                pa.w[0] = pk[4 * kk + 0]; pa.w[1] = pk[4 * kk + 1];
                pa.w[2] = pk[4 * kk + 2]; pa.w[3] = pk[4 * kk + 3];
                #pragma unroll
                for (int nt = 0; nt < 4; ++nt) {
                    bf16x8 vb = *reinterpret_cast<const bf16x8*>(&Vt[cur][nt * 16 + c][kk * 32 + g * 8]);
                    yacc[nt] = __builtin_amdgcn_mfma_f32_16x16x32_bf16(pa.v, vb, yacc[nt], 0, 0, 0);
                }
            }
            __builtin_amdgcn_s_setprio(0);
        }
    }

    // ---- epilogue: finish l (2 shfl), broadcast inv to PV layout, store ----
    float lf = l_run;
    lf += __shfl_xor(lf, 16, 64);
    lf += __shfl_xor(lf, 32, 64);
    const float inv = 1.0f / lf;              // for row q = qw0 + c
    const int ii = __float_as_int(inv);
    float invr[4];
    #pragma unroll
    for (int r = 0; r < 4; ++r)
        invr[r] = __int_as_float(__builtin_amdgcn_ds_bpermute((4 * g + r) * 4, ii));
    #pragma unroll
    for (int r = 0; r < 4; ++r) {
        const size_t row = (size_t)(bb * T_ + q0 + qw0 + 4 * g + r);
        #pragma unroll
        for (int nt = 0; nt < 4; ++nt) {
            const int col = h * HD_ + 16 * nt + c;
            Yu[row * C_ + col] = f2bf(yacc[nt][r] * invr[r]);
        }
    }
}

extern "C" void kernel_launch(void* const* d_in, const int* in_sizes, int n_in,
                              void* d_out, int out_size, void* d_ws, size_t ws_size,
                              hipStream_t stream) {
    const float* x      = (const float*)d_in[0];
    const float* w_qkv  = (const float*)d_in[1];
    const float* w_proj = (const float*)d_in[2];
    float* out = (float*)d_out;

    const size_t HELEMS = (size_t)B_ * NH_ * T_ * HD_;   // 4,194,304
    unsigned short* Qb   = (unsigned short*)d_ws;
    unsigned short* Kb   = Qb + HELEMS;
    unsigned short* Vraw = Kb + HELEMS;       // row-major V; later reused as Yb
    unsigned short* Yb   = Vraw;              //   (V dead after post)
    unsigned short* Xb   = Vraw + HELEMS;     // bf16 x; later reused as Vt
    unsigned short* Vt   = Xb;                //   (x dead after qkv_gemm)
    unsigned short* Wqt  = Xb + HELEMS;       // 3072x1024 bf16 (6MB)
    unsigned short* Wpt  = Wqt + (size_t)3 * C_ * C_;    // own 1024x1024 (2MB)
                                              // total 40 MB

    prep<<<3072, 256, 0, stream>>>(x, w_qkv, w_proj, Xb, Wqt, Wpt);
    qkv_gemm_mfma<<<768, 256, 0, stream>>>(Xb, Wqt, Qb, Kb, Vraw);
    post<<<1024, 256, 0, stream>>>(Vraw, Vt);
    attn_mfma<<<512, 512, 0, stream>>>(Qb, Kb, Vt, Yb);
    proj_gemm_mfma<<<512, 256, 0, stream>>>(Yb, Wpt, out);
}